// Round 2
// baseline (52826.135 us; speedup 1.0000x reference)
//
#include <hip/hip_runtime.h>
#include <hip/hip_bf16.h>

#define B_   2048
#define L_   128
#define V_   64
#define H_   501
#define T_   127
#define BT_  16
#define NWG_ 128
#define NTH_ 512

typedef __attribute__((ext_vector_type(8))) short short8;
typedef __attribute__((ext_vector_type(4))) float f32x4;

#define MFMA(acc, a, b) acc = __builtin_amdgcn_mfma_f32_16x16x32_bf16((a), (b), (acc), 0, 0, 0)

__device__ __forceinline__ float sigm(float x){ return 1.f/(1.f + __expf(-x)); }
__device__ __forceinline__ float tanh_(float x){ float e = __expf(2.f*x); return 1.f - 2.f/(e + 1.f); }
__device__ __forceinline__ unsigned short f2bf(float x){
  unsigned u = __float_as_uint(x);
  u += 0x7fffu + ((u >> 16) & 1u);
  return (unsigned short)(u >> 16);
}

// ---- prologue kernels ----

// Frag-linear weight pack: dst[mg][jt][s][lane][8], mg = mtx*3+gate (mtx: whh0,wih1,whh1,wih2,whh2)
// element = W[gate*H + jt*16 + (lane&15)][s*32 + ((lane>>4)&3)*8 + e]  (0-padded)
__global__ void k_pack_w(const float* w0,const float* w1,const float* w2,const float* w3,const float* w4,
                         unsigned short* dst){
  int idx = blockIdx.x*256 + threadIdx.x;
  if (idx >= 15*32*16*512) return;
  int e  = idx & 7;
  int l  = (idx>>3) & 63;
  int s  = (idx>>9) & 15;
  int jt = (idx>>13) & 31;
  int mg = idx >> 18;            // 0..14
  int mtx = mg/3, g = mg%3;
  int j = jt*16 + (l & 15);
  int k = s*32 + ((l>>4)&3)*8 + e;
  const float* src = (mtx==0)?w0:(mtx==1)?w1:(mtx==2)?w2:(mtx==3)?w3:w4;
  float v = 0.f;
  if (j < H_ && k < H_) v = src[(size_t)(g*H_ + j)*H_ + k];
  dst[idx] = f2bf(v);
}

// LinW frag-linear: dst[jt=4][s=16][lane][8]; j = jt*16+(l&15) (vocab), k = s*32+((l>>4)&3)*8+e
__global__ void k_pack_linw(const float* lw, unsigned short* dst){
  int idx = blockIdx.x*256 + threadIdx.x;
  if (idx >= 4*16*512) return;
  int e  = idx & 7;
  int l  = (idx>>3) & 63;
  int s  = (idx>>9) & 15;
  int jt = idx >> 13;
  int j = jt*16 + (l & 15);
  int k = s*32 + ((l>>4)&3)*8 + e;
  dst[idx] = f2bf((k < H_) ? lw[j*H_ + k] : 0.f);
}

// dst[bias][g][j]: order bhh0, bih1, bhh1, bih2, bhh2 (matches mtx indexing)
__global__ void k_pack_bias(const float* b0,const float* b1,const float* b2,const float* b3,const float* b4,
                            float* dst){
  int idx = blockIdx.x*256 + threadIdx.x;
  if (idx >= 5*1536) return;
  int j = idx & 511; int g = (idx>>9)%3; int l = idx/1536;
  const float* s = (l==0)?b0:(l==1)?b1:(l==2)?b2:(l==3)?b3:b4;
  dst[idx] = (j < H_) ? s[g*H_ + j] : 0.f;
}

// EW[v][g][j] = sum_k emb[v][k] * wih0[g*501+j][k], k<128
__global__ void k_ew(const float* emb, const float* wih0, float* EW){
  int idx = blockIdx.x*256 + threadIdx.x;
  if (idx >= 64*1536) return;
  int j = idx & 511; int g = (idx>>9)%3; int v = idx/1536;
  float s = 0.f;
  if (j < H_){
    const float* wr = wih0 + (size_t)(g*H_ + j)*257;
    const float* e  = emb + v*128;
    for (int k=0;k<128;++k) s += e[k]*wr[k];
  }
  EW[idx] = s;
}

// Cb[b][g][j] = bih0[gj] + z[b,:] @ wih0[gj, 128:256] + y[b]*wih0[gj, 256]
__global__ void k_cb(const float* z, const float* y, const float* bih0, const float* wih0, float* Cb){
  int idx = blockIdx.x*256 + threadIdx.x;
  if (idx >= B_*1536) return;
  int j = idx & 511; int g = (idx>>9)%3; int b = idx/1536;
  float s = 0.f;
  if (j < H_){
    int row = g*H_ + j;
    const float* wr = wih0 + (size_t)row*257 + 128;
    const float* zr = z + b*128;
    s = bih0[row] + y[b]*wr[128];
    for (int k=0;k<128;++k) s += zr[k]*wr[k];
  }
  Cb[idx] = s;
}

__global__ void k_out0(float* out){
  int idx = blockIdx.x*256 + threadIdx.x;
  if (idx >= B_*64) return;
  int v = idx & 63, b = idx >> 6;
  out[(size_t)b*(L_*V_) + v] = (v==1) ? 1.f : 0.f;
}

// ---- main persistent GRU kernel ----

__global__ __launch_bounds__(NTH_, 2) void k_gru(
  const int* __restrict__ xin, const unsigned short* __restrict__ Wf,
  const unsigned short* __restrict__ LinWf, const float* __restrict__ EW,
  const float* __restrict__ Cb, const float* __restrict__ biasP,
  const float* __restrict__ linb, float* __restrict__ out)
{
  __shared__ unsigned short hsh[3*16*512];   // 48 KB bf16 h (MFMA A source), XOR-swizzled
  __shared__ float          hmf[3*16*512];   // 96 KB fp32 h master
  // 144 KB total LDS -> exactly 1 WG/CU -> 128 WGs spread over 128 CUs

  const int tid  = threadIdx.x;
  const int wid  = tid >> 6;
  const int lane = tid & 63;
  const int lrow = lane >> 4;
  const int lcol = lane & 15;
  const int b0   = blockIdx.x * BT_;

  for (int i = tid; i < 3*16*512; i += NTH_){ hsh[i] = 0; hmf[i] = 0.f; }
  __syncthreads();

  const unsigned short* wl = Wf   + lane*8;   // per-lane frag base (16B per lane)
  const unsigned short* ll = LinWf + lane*8;

  // A-fragment from swizzled bf16 LDS: row=lcol, k = s*32 + lrow*8 .. +8
  auto afrag = [&](int layer, int s)->short8 {
    int byte = (lcol<<10) + (s<<6) + (lrow<<4);
    byte ^= ((lcol&7)<<4);
    return *(const short8*)((const char*)hsh + layer*16384 + byte);
  };
  // fp32 master h address (swizzled to break 4-way m-conflicts)
  auto hmi = [&](int layer, int m, int j)->int {
    return layer*8192 + m*512 + (j ^ ((m&3)<<2));
  };

  short8 rb0[4][3];   // layer0 ring
  short8 rb1[4][6];   // layer1/2 ring
  short8 rbL[4];      // logits ring
  int tokn[4];

  auto L0LD = [&](int it, short8* d){
    int tt = it>>4, s = it&15, jt = wid + 8*tt;
    size_t o = (size_t)jt*8192 + (size_t)s*512;
    d[0] = *(const short8*)(wl + o);
    d[1] = *(const short8*)(wl + o + 262144);
    d[2] = *(const short8*)(wl + o + 524288);
  };
  auto L12LD = [&](int l, int it, short8* d){
    int tt = it>>4, s = it&15, jt = wid + 8*tt;
    int mI = 1 + (l-1)*2;
    size_t o = (size_t)jt*8192 + (size_t)s*512;
    const unsigned short* pI = wl + (size_t)mI*786432 + o;
    d[0] = *(const short8*)(pI);
    d[1] = *(const short8*)(pI + 262144);
    d[2] = *(const short8*)(pI + 524288);
    d[3] = *(const short8*)(pI + 786432);
    d[4] = *(const short8*)(pI + 1048576);
    d[5] = *(const short8*)(pI + 1310720);
  };
  auto LLLD = [&](int it, short8* d){
    int s = it & 15;
    d[0] = *(const short8*)(ll + (size_t)wid*8192 + (size_t)s*512);
  };

  const f32x4 z4 = {0.f,0.f,0.f,0.f};

  // prime layer0 ring for step 0
  #pragma unroll
  for (int pf=0; pf<4; ++pf) L0LD(pf, rb0[pf]);

  #pragma unroll 1
  for (int t = 0; t < T_; ++t){
    int tok[4];
    #pragma unroll
    for (int i=0;i<4;++i) tok[i] = (t==0) ? 1 : tokn[i];
    #pragma unroll
    for (int i=0;i<4;++i) tokn[i] = xin[(b0+lrow*4+i)*L_ + (t+1)];  // prefetch next step's tokens

    // ---------- LAYER 0 ----------
    {
      f32x4 aR=z4, aZ=z4, aN=z4;
      float gr[4], gz[4], gn[4], br=0.f, bz=0.f, bn=0.f;
      #pragma unroll 4
      for (int it=0; it<64; ++it){
        const int tt = it>>4, s = it&15;
        if (s==0){ aR=z4; aZ=z4; aN=z4; }
        short8 a = afrag(0, s);
        MFMA(aR, a, rb0[it&3][0]);
        MFMA(aZ, a, rb0[it&3][1]);
        MFMA(aN, a, rb0[it&3][2]);
        if (it < 60) L0LD(it+4, rb0[it&3]);
        else         L12LD(1, it-60, rb1[(it-60)&3]);   // prime layer1 ring
        if (s==8){
          const int j = (wid + 8*tt)*16 + lcol;
          br = biasP[j]; bz = biasP[512+j]; bn = biasP[1024+j];
          #pragma unroll
          for (int i=0;i<4;++i){
            const float* ewp = EW + tok[i]*1536;
            const float* cbp = Cb + (size_t)(b0+lrow*4+i)*1536;
            gr[i] = ewp[j]      + cbp[j];
            gz[i] = ewp[512+j]  + cbp[512+j];
            gn[i] = ewp[1024+j] + cbp[1024+j];
          }
        }
        if (s==15){
          const int j = (wid + 8*tt)*16 + lcol;
          #pragma unroll
          for (int i=0;i<4;++i){
            const int m = lrow*4+i;
            float hp = hmf[hmi(0,m,j)];
            float r  = sigm(gr[i] + aR[i] + br);
            float zg = sigm(gz[i] + aZ[i] + bz);
            float n  = tanh_(gn[i] + r*(aN[i] + bn));
            float hnew = (1.f - zg)*n + zg*hp;
            hmf[hmi(0,m,j)] = (j < H_) ? hnew : 0.f;
          }
        }
      }
    }
    __syncthreads();
    #pragma unroll
    for (int tt=0; tt<4; ++tt){
      const int j = (wid + 8*tt)*16 + lcol;
      #pragma unroll
      for (int i=0;i<4;++i){
        const int m = lrow*4+i;
        float v = hmf[hmi(0,m,j)];
        int byte = (m<<10) + (j<<1); byte ^= ((m&7)<<4);
        *(unsigned short*)((char*)hsh + byte) = f2bf(v);
      }
    }
    __syncthreads();

    // ---------- LAYERS 1, 2 ----------
    #pragma unroll 1
    for (int l = 1; l <= 2; ++l){
      const int mI = 1 + (l-1)*2, mH = mI+1;
      {
        f32x4 aR=z4, aZ=z4, aNI=z4, aNH=z4;
        float bir=0.f,biz=0.f,bin=0.f,bhr=0.f,bhz=0.f,bhn=0.f;
        #pragma unroll 4
        for (int it=0; it<64; ++it){
          const int tt = it>>4, s = it&15;
          if (s==0){ aR=z4; aZ=z4; aNI=z4; aNH=z4; }
          short8 ap = afrag(l-1, s);
          short8 as = afrag(l,   s);
          MFMA(aR,  ap, rb1[it&3][0]);
          MFMA(aZ,  ap, rb1[it&3][1]);
          MFMA(aNI, ap, rb1[it&3][2]);
          MFMA(aR,  as, rb1[it&3][3]);
          MFMA(aZ,  as, rb1[it&3][4]);
          MFMA(aNH, as, rb1[it&3][5]);
          if (it < 60) L12LD(l, it+4, rb1[it&3]);
          else if (l==1) L12LD(2, it-60, rb1[(it-60)&3]);     // prime layer2 ring
          else if (wid < 4) LLLD(it-60, &rbL[(it-60)&3]);     // prime logits ring
          if (s==8){
            const int j = (wid + 8*tt)*16 + lcol;
            bir = biasP[mI*1536 + j]; biz = biasP[mI*1536 + 512 + j]; bin = biasP[mI*1536 + 1024 + j];
            bhr = biasP[mH*1536 + j]; bhz = biasP[mH*1536 + 512 + j]; bhn = biasP[mH*1536 + 1024 + j];
          }
          if (s==15){
            const int j = (wid + 8*tt)*16 + lcol;
            #pragma unroll
            for (int i=0;i<4;++i){
              const int m = lrow*4+i;
              float hp = hmf[hmi(l,m,j)];
              float r  = sigm(aR[i] + bir + bhr);
              float zg = sigm(aZ[i] + biz + bhz);
              float n  = tanh_(aNI[i] + bin + r*(aNH[i] + bhn));
              float hnew = (1.f - zg)*n + zg*hp;
              hmf[hmi(l,m,j)] = (j < H_) ? hnew : 0.f;
            }
          }
        }
      }
      __syncthreads();
      #pragma unroll
      for (int tt=0; tt<4; ++tt){
        const int j = (wid + 8*tt)*16 + lcol;
        #pragma unroll
        for (int i=0;i<4;++i){
          const int m = lrow*4+i;
          float v = hmf[hmi(l,m,j)];
          int byte = (m<<10) + (j<<1); byte ^= ((m&7)<<4);
          *(unsigned short*)((char*)hsh + l*16384 + byte) = f2bf(v);
        }
      }
      __syncthreads();
    }

    // ---------- logits (waves 0-3); waves 4-7 fall through ----------
    if (wid < 4){
      f32x4 acc = z4;
      #pragma unroll 4
      for (int it=0; it<16; ++it){
        short8 a = afrag(2, it);
        MFMA(acc, a, rbL[it&3]);
        if (it < 12) LLLD(it+4, &rbL[it&3]);
      }
      const int j = wid*16 + lcol;
      float lb = linb[j];
      #pragma unroll
      for (int i=0;i<4;++i){
        const int m = lrow*4+i;
        out[(size_t)(b0+m)*(L_*V_) + (size_t)(t+1)*V_ + j] = acc[i] + lb;
      }
    }

    // prime next step's layer0 ring (all waves)
    #pragma unroll
    for (int pf=0; pf<4; ++pf) L0LD(pf, rb0[pf]);
  }
}

extern "C" void kernel_launch(void* const* d_in, const int* in_sizes, int n_in,
                              void* d_out, int out_size, void* d_ws, size_t ws_size,
                              hipStream_t stream)
{
  const float* z    = (const float*)d_in[0];
  const float* y    = (const float*)d_in[1];
  const int*   xin  = (const int*)d_in[2];
  const float* emb  = (const float*)d_in[3];
  const float* linw = (const float*)d_in[4];
  const float* linb = (const float*)d_in[5];
  const float* wih0 = (const float*)d_in[6];
  const float* whh0 = (const float*)d_in[7];
  const float* bih0 = (const float*)d_in[8];
  const float* bhh0 = (const float*)d_in[9];
  const float* wih1 = (const float*)d_in[10];
  const float* whh1 = (const float*)d_in[11];
  const float* bih1 = (const float*)d_in[12];
  const float* bhh1 = (const float*)d_in[13];
  const float* wih2 = (const float*)d_in[14];
  const float* whh2 = (const float*)d_in[15];
  const float* bih2 = (const float*)d_in[16];
  const float* bhh2 = (const float*)d_in[17];
  float* out = (float*)d_out;

  char* ws = (char*)d_ws;
  unsigned short* Wf    = (unsigned short*)(ws);                               // 7,864,320 B
  unsigned short* LinWf = (unsigned short*)(ws + 7864320);                     //    65,536 B
  float* EW    = (float*)(ws + 7864320 + 65536);                               //   393,216 B
  float* Cb    = (float*)(ws + 7864320 + 65536 + 393216);                      // 12,582,912 B
  float* BiasP = (float*)(ws + 7864320 + 65536 + 393216 + 12582912);           //    30,720 B

  k_pack_w   <<<(15*32*16*512 + 255)/256, 256, 0, stream>>>(whh0, wih1, whh1, wih2, whh2, Wf);
  k_pack_linw<<<(4*16*512     + 255)/256, 256, 0, stream>>>(linw, LinWf);
  k_pack_bias<<<(5*1536       + 255)/256, 256, 0, stream>>>(bhh0, bih1, bhh1, bih2, bhh2, BiasP);
  k_ew       <<<(64*1536      + 255)/256, 256, 0, stream>>>(emb, wih0, EW);
  k_cb       <<<(B_*1536      + 255)/256, 256, 0, stream>>>(z, y, bih0, wih0, Cb);
  k_out0     <<<(B_*64        + 255)/256, 256, 0, stream>>>(out);
  k_gru      <<<NWG_, NTH_, 0, stream>>>(xin, Wf, LinWf, EW, Cb, BiasP, linb, out);
}